// Round 13
// baseline (119.894 us; speedup 1.0000x reference)
//
#include <hip/hip_runtime.h>

#define EPS 1e-10f

constexpr int B_ = 64, K_ = 4, M_ = 3, P_ = 65536;
constexpr int THREADS = 128;                // 2-wave blocks
constexpr int CHUNK = 512;                  // pixels per block (1 float4/plane/thread)
constexpr int BPB = P_ / CHUNK;             // 128 -> grid 8192
constexpr int NS = 32;                      // sums stride
constexpr int NACC = 29;                    // s0..3 t4..15 u16..27 n28

// ---- s13_stats: per-(b,k) weighted sums + ROI count ------------------------
__global__ __launch_bounds__(THREADS) void s13_stats(
    const float* __restrict__ pred, const float* __restrict__ inp,
    const int* __restrict__ heart, float* __restrict__ sums)
{
    const int b     = blockIdx.x / BPB;
    const int chunk = blockIdx.x % BPB;
    const int tid   = threadIdx.x;
    const int v     = chunk * (CHUNK / 4) + tid;      // float4 index

    const float4* pb = (const float4*)(pred + (size_t)b * K_ * P_);
    const float4* ib = (const float4*)(inp  + (size_t)b * M_ * P_);
    const int4*   hb = (const int4*)(heart + (size_t)b * P_);

    const int4 h4 = hb[v];
    float4 pk[K_]; float4 xm[M_];
    #pragma unroll
    for (int k = 0; k < K_; ++k) pk[k] = pb[k * (P_ / 4) + v];
    #pragma unroll
    for (int m = 0; m < M_; ++m) xm[m] = ib[m * (P_ / 4) + v];

    float sacc[K_], tacc[K_][M_], uacc[K_][M_], nacc = 0.f;
    #pragma unroll
    for (int k = 0; k < K_; ++k) {
        sacc[k] = 0.f;
        #pragma unroll
        for (int m = 0; m < M_; ++m) { tacc[k][m] = 0.f; uacc[k][m] = 0.f; }
    }

    #define PIX1(C) do {                                                      \
        const float w = (h4.C == 1) ? 1.f : 0.f;                              \
        nacc += w;                                                            \
        _Pragma("unroll")                                                     \
        for (int k = 0; k < K_; ++k) {                                        \
            const float pw = pk[k].C * w;                                     \
            sacc[k] += pw;                                                    \
            _Pragma("unroll")                                                 \
            for (int m = 0; m < M_; ++m) {                                    \
                const float x = xm[m].C;                                      \
                tacc[k][m] = fmaf(pw,     x, tacc[k][m]);                     \
                uacc[k][m] = fmaf(pw * x, x, uacc[k][m]);                     \
            }                                                                 \
        }                                                                     \
    } while (0)
    PIX1(x); PIX1(y); PIX1(z); PIX1(w);
    #undef PIX1

    float acc[NACC];
    #pragma unroll
    for (int k = 0; k < K_; ++k) {
        acc[k] = sacc[k];
        #pragma unroll
        for (int m = 0; m < M_; ++m) {
            acc[4  + k * M_ + m] = tacc[k][m];
            acc[16 + k * M_ + m] = uacc[k][m];
        }
    }
    acc[28] = nacc;

    __shared__ float red[2][NACC];
    const int lane = tid & 63, wid = tid >> 6;
    #pragma unroll
    for (int i = 0; i < NACC; ++i) {
        float x = acc[i];
        #pragma unroll
        for (int off = 32; off; off >>= 1) x += __shfl_down(x, off);
        if (lane == 0) red[wid][i] = x;
    }
    __syncthreads();
    if (tid < NACC)
        atomicAdd(&sums[b * NS + tid], red[0][tid] + red[1][tid]);
}

// ---- s13_loss: inline derivation + mixture ll, per-b partial ---------------
__global__ __launch_bounds__(THREADS) void s13_loss(
    const float* __restrict__ pred, const float* __restrict__ inp,
    const int* __restrict__ heart, const float* __restrict__ sums,
    float* __restrict__ partials)
{
    const int b     = blockIdx.x / BPB;
    const int chunk = blockIdx.x % BPB;
    const int tid   = threadIdx.x;
    const int v     = chunk * (CHUNK / 4) + tid;

    // derivation from 29 broadcast sums (one cache line)
    const float* sb = sums + b * NS;
    float mu[K_][M_], iv[K_][M_], ck[K_];
    #pragma unroll
    for (int k = 0; k < K_; ++k) {
        const float s = sb[k] + EPS;
        const float inv_s = 1.f / s;
        float c = 1.f;
        #pragma unroll
        for (int m = 0; m < M_; ++m) {
            const float t = sb[4  + k * M_ + m];
            const float u = sb[16 + k * M_ + m];
            const float muv = t * inv_s;
            const float var = fmaf(-muv, muv, u * inv_s) + EPS;
            mu[k][m] = muv;
            iv[k][m] = 0.5f / var;
            c *= rsqrtf(6.283185307179586f * var);
        }
        ck[k] = c;
    }
    const float invn = 1.f / (sb[28] * (float)B_);

    const float4* pb = (const float4*)(pred + (size_t)b * K_ * P_);
    const float4* ib = (const float4*)(inp  + (size_t)b * M_ * P_);
    const int4*   hb = (const int4*)(heart + (size_t)b * P_);

    const int4 h4 = hb[v];
    float4 pk[K_]; float4 xm[M_];
    #pragma unroll
    for (int k = 0; k < K_; ++k) pk[k] = pb[k * (P_ / 4) + v];
    #pragma unroll
    for (int m = 0; m < M_; ++m) xm[m] = ib[m * (P_ / 4) + v];

    float part = 0.f;
    #define PIX3(C) do {                                                      \
        const float w = (h4.C == 1) ? 1.f : 0.f;                              \
        float mix = EPS;                                                      \
        _Pragma("unroll")                                                     \
        for (int k = 0; k < K_; ++k) {                                        \
            float e = 0.f;                                                    \
            _Pragma("unroll")                                                 \
            for (int m = 0; m < M_; ++m) {                                    \
                const float d = xm[m].C - mu[k][m];                           \
                e = fmaf(-(d * d), iv[k][m], e);                              \
            }                                                                 \
            mix = fmaf(pk[k].C * ck[k], __expf(e), mix);                      \
        }                                                                     \
        part = fmaf(w, __logf(mix), part);                                    \
    } while (0)
    PIX3(x); PIX3(y); PIX3(z); PIX3(w);
    #undef PIX3

    __shared__ float red[2];
    const int lane = tid & 63, wid = tid >> 6;
    float x = part;
    #pragma unroll
    for (int off = 32; off; off >>= 1) x += __shfl_down(x, off);
    if (lane == 0) red[wid] = x;
    __syncthreads();
    if (tid == 0)
        atomicAdd(&partials[b], -(red[0] + red[1]) * invn);
}

// ---- s13_final: sum the 64 per-b partials into out[0] ----------------------
__global__ void s13_final(const float* __restrict__ partials, float* __restrict__ out)
{
    const int tid = threadIdx.x;            // 64 threads
    float x = partials[tid];
    #pragma unroll
    for (int off = 32; off; off >>= 1) x += __shfl_down(x, off);
    if (tid == 0) out[0] = x;
}

extern "C" void kernel_launch(void* const* d_in, const int* in_sizes, int n_in,
                              void* d_out, int out_size, void* d_ws, size_t ws_size,
                              hipStream_t stream)
{
    const float* pred  = (const float*)d_in[0];
    const float* inp   = (const float*)d_in[1];
    const int*   heart = (const int*)d_in[2];
    float* out      = (float*)d_out;
    float* sums     = (float*)d_ws;                 // B*32 floats
    float* partials = (float*)d_ws + B_ * NS;       // B floats

    hipMemsetAsync(sums, 0, (B_ * NS + B_) * sizeof(float), stream);

    s13_stats<<<B_ * BPB, THREADS, 0, stream>>>(pred, inp, heart, sums);
    s13_loss <<<B_ * BPB, THREADS, 0, stream>>>(pred, inp, heart, sums, partials);
    s13_final<<<1, 64, 0, stream>>>(partials, out);
}